// Round 11
// baseline (906.043 us; speedup 1.0000x reference)
//
#include <hip/hip_runtime.h>

#define NN 100000
#define NE 1600000
#define PSHIFT 9
#define PSZ 512
#define NP ((NN + PSZ - 1) / PSZ)             // 196
#define BCHUNK 8192
#define NBIN ((NE + BCHUNK - 1) / BCHUNK)     // 196
#define SRCMASK 0x1FFFF                       // 17 bits (NN < 131072)
#define BUCKET 9216                           // per-partition col slots
#define GMTILES ((NN + 63) / 64)              // 1563
#define GEMM_GB 512                           // gemm grid (blocks)
#define NCHUNK 1563                           // gather chunks (64 nodes each)
#define GGRID 2048                            // gather grid

typedef __attribute__((ext_vector_type(8))) short short8;
typedef __attribute__((ext_vector_type(4))) float f32x4;

__device__ __forceinline__ ushort f2bf(float f) {
    uint u = __float_as_uint(f);
    return (ushort)((u + 0x7FFFu + ((u >> 16) & 1u)) >> 16);   // RNE
}
__device__ __forceinline__ float bflo(uint u) { return __uint_as_float(u << 16); }
__device__ __forceinline__ float bfhi(uint u) { return __uint_as_float(u & 0xffff0000u); }
__device__ __forceinline__ uint packbf(float a, float b) {
    return (uint)f2bf(a) | ((uint)f2bf(b) << 16);
}
__device__ __forceinline__ int xcc_id() {
    // s_getreg_b32 hwreg(HW_REG_XCC_ID=20, offset 0, size 4)  [m09-verified]
    return (int)(__builtin_amdgcn_s_getreg((3u << 11) | 20u) & 7u);
}

// ---------------------------------------------------------------------------
// Prep: block 0 inits gcur[p] = p*BUCKET and zeroes gather cursors;
// blocks 1.. cast weights to bf16 (transposed, fused [Wl|Wr]).
// ---------------------------------------------------------------------------
__global__ __launch_bounds__(256) void k_prep(const float* __restrict__ W1l,
                                              const float* __restrict__ W1r,
                                              const float* __restrict__ W2l,
                                              const float* __restrict__ W2r,
                                              ushort* __restrict__ WbT1,
                                              ushort* __restrict__ WbT2,
                                              int* __restrict__ gcur,
                                              int* __restrict__ cnt1,
                                              int* __restrict__ cnt2)
{
    const int tid = threadIdx.x;
    if (blockIdx.x == 0) {
        if (tid < NP) gcur[tid] = tid * BUCKET;
        if (tid < 8) { cnt1[tid] = 0; cnt2[tid] = 0; }
        return;
    }
    int i = (blockIdx.x - 1) * 256 + tid;
    if (i < 256 * 128) {
        int c = i >> 7, k = i & 127;
        float v = (c < 128) ? W1l[k * 128 + c] : W1r[k * 128 + (c - 128)];
        WbT1[i] = f2bf(v);
    } else if (i < 256 * 128 + 128 * 128) {
        int j = i - 256 * 128;
        int c = j >> 7, k = j & 127;
        float v = (c < 64) ? W2l[k * 64 + c] : W2r[k * 64 + (c - 64)];
        WbT2[j] = f2bf(v);
    }
}

// ---------------------------------------------------------------------------
// Binning: per-block LDS histogram of partition, one global atomic per
// (block, partition), write packed = src | (dlocal << 17) into fixed buckets.
// ---------------------------------------------------------------------------
__global__ __launch_bounds__(256) void k_binning(const int* __restrict__ src,
                                                 const int* __restrict__ dst,
                                                 int* __restrict__ gcur,
                                                 uint* __restrict__ packed)
{
    __shared__ int cnt[256];
    __shared__ int base[256];
    const int tid = threadIdx.x;
    const long e0 = (long)blockIdx.x * BCHUNK;
    cnt[tid] = 0;
    __syncthreads();
    for (int i = tid; i < BCHUNK; i += 256) {
        long e = e0 + i;
        if (e < NE) atomicAdd(&cnt[dst[e] >> PSHIFT], 1);
    }
    __syncthreads();
    if (cnt[tid] > 0) base[tid] = atomicAdd(&gcur[tid], cnt[tid]);
    cnt[tid] = 0;
    __syncthreads();
    for (int i = tid; i < BCHUNK; i += 256) {
        long e = e0 + i;
        if (e < NE) {
            int d = dst[e], s = src[e];
            int p = d >> PSHIFT;
            int ofs = atomicAdd(&cnt[p], 1);
            packed[base[p] + ofs] = (uint)s | ((uint)(d & (PSZ - 1)) << 17);
        }
    }
}

// ---------------------------------------------------------------------------
// Per-partition fill: count, scan, rowptr/rowend, place col in bucket.
// ---------------------------------------------------------------------------
__global__ __launch_bounds__(256) void k_pfill(const uint* __restrict__ packed,
                                               const int* __restrict__ gcur,
                                               int* __restrict__ rowptr,
                                               int* __restrict__ rowend,
                                               int* __restrict__ col)
{
    __shared__ int cnt[PSZ];
    __shared__ int cur[PSZ];
    __shared__ int tot[256];
    const int p   = blockIdx.x;
    const int tid = threadIdx.x;
    const int beg = p * BUCKET, end = gcur[p];
    cnt[tid] = 0; cnt[tid + 256] = 0;
    __syncthreads();
    for (int i = beg + tid; i < end; i += 256)
        atomicAdd(&cnt[packed[i] >> 17], 1);
    __syncthreads();
    int v0 = cnt[tid * 2], v1 = cnt[tid * 2 + 1];
    int s  = v0 + v1;
    tot[tid] = s;
    __syncthreads();
    for (int off = 1; off < 256; off <<= 1) {
        int t = (tid >= off) ? tot[tid - off] : 0;
        __syncthreads();
        tot[tid] += t;
        __syncthreads();
    }
    int ex = tot[tid] - s + beg;
    cur[tid * 2]     = ex;
    cur[tid * 2 + 1] = ex + v0;
    int n0 = p * PSZ;
    if (n0 + tid * 2 < NN) {
        rowptr[n0 + tid * 2] = ex;
        rowend[n0 + tid * 2] = ex + v0;
    }
    if (n0 + tid * 2 + 1 < NN) {
        rowptr[n0 + tid * 2 + 1] = ex + v0;
        rowend[n0 + tid * 2 + 1] = ex + v0 + v1;
    }
    __syncthreads();
    for (int i = beg + tid; i < end; i += 256) {
        uint v = packed[i];
        int pos = atomicAdd(&cur[v >> 17], 1);
        col[pos] = (int)(v & SRCMASK);
    }
}

// ---------------------------------------------------------------------------
// Pipelined dual-GEMM: [z | y] = A @ [Wl | Wr] (+bias on y half).
// AMODE 0: A fp32 row-major; AMODE 1: A bf16 sliced [8][NN][16].
// Outputs SLICED: CB=2 -> z,y bf16 [8][NN][16]; CB=1 -> z bf16 [8][NN][8],
// y fp32 [8][NN][8] (YF32). B fragments in registers; A tile dbuf LDS.
// ---------------------------------------------------------------------------
template <int AMODE, int CB, bool YF32>
__global__ __launch_bounds__(512) void k_gemm(const void* __restrict__ Ap,
                                              const ushort* __restrict__ Bt,
                                              const float* __restrict__ bias,
                                              ushort* __restrict__ zb,
                                              void* __restrict__ yout)
{
    constexpr int ZW = CB * 64;
    __shared__ ushort As[2][64 * 128];         // 2 x 16 KB

    const int tid  = threadIdx.x;
    const int wid  = tid >> 6, lane = tid & 63;
    const int lr   = lane & 15;
    const int lk   = (lane >> 4) << 3;

    short8 bfr[4][CB];
#pragma unroll
    for (int ks = 0; ks < 4; ++ks)
#pragma unroll
        for (int nf = 0; nf < CB; ++nf) {
            int colB = wid * (16 * CB) + nf * 16 + lr;
            bfr[ks][nf] = *reinterpret_cast<const short8*>(
                Bt + (size_t)colB * 128 + ks * 32 + lk);
        }

    const int p0 = tid * 16, p1 = p0 + 8192;
    const int r0 = p0 >> 8, r1 = p1 >> 8;
    const int d0 = p0 ^ ((r0 & 7) << 4);
    const int d1 = p1 ^ ((r1 & 7) << 4);
    const int e0 = (p0 & 255) >> 1;
    const int e1 = (p1 & 255) >> 1;

    const short8 zero8 = {0, 0, 0, 0, 0, 0, 0, 0};
    short8 sA0, sA1;

    auto loadA = [&](int gr, int eo) -> short8 {
        if (gr >= NN) return zero8;
        if (AMODE == 0) {
            const float* A = (const float*)Ap;
            float4 f0 = *reinterpret_cast<const float4*>(A + (size_t)gr * 128 + eo);
            float4 f1 = *reinterpret_cast<const float4*>(A + (size_t)gr * 128 + eo + 4);
            short8 v;
            v[0] = (short)f2bf(f0.x); v[1] = (short)f2bf(f0.y);
            v[2] = (short)f2bf(f0.z); v[3] = (short)f2bf(f0.w);
            v[4] = (short)f2bf(f1.x); v[5] = (short)f2bf(f1.y);
            v[6] = (short)f2bf(f1.z); v[7] = (short)f2bf(f1.w);
            return v;
        } else {
            const ushort* A = (const ushort*)Ap;   // sliced [8][NN][16]
            return *reinterpret_cast<const short8*>(
                A + (size_t)(eo >> 4) * NN * 16 + (size_t)gr * 16 + (eo & 15));
        }
    };

    int t = blockIdx.x;
    sA0 = loadA(t * 64 + r0, e0);
    sA1 = loadA(t * 64 + r1, e1);

    int cur = 0;
    for (; t < GMTILES; t += GEMM_GB) {
        char* wbase = reinterpret_cast<char*>(As[cur]);
        *reinterpret_cast<short8*>(wbase + d0) = sA0;
        *reinterpret_cast<short8*>(wbase + d1) = sA1;
        __syncthreads();

        int tn = t + GEMM_GB;
        if (tn < GMTILES) {
            sA0 = loadA(tn * 64 + r0, e0);
            sA1 = loadA(tn * 64 + r1, e1);
        }

        f32x4 acc[4][CB];
#pragma unroll
        for (int mi = 0; mi < 4; ++mi)
#pragma unroll
            for (int nf = 0; nf < CB; ++nf) acc[mi][nf] = f32x4{0.f, 0.f, 0.f, 0.f};

        const char* pA = reinterpret_cast<const char*>(As[cur]);
#pragma unroll
        for (int ks = 0; ks < 4; ++ks) {
            int k2 = (ks * 32 + lk) * 2;
            short8 a[4];
#pragma unroll
            for (int mi = 0; mi < 4; ++mi) {
                int r = mi * 16 + lr;
                int byte = (r * 256 + k2) ^ ((r & 7) << 4);
                a[mi] = *reinterpret_cast<const short8*>(pA + byte);
            }
#pragma unroll
            for (int mi = 0; mi < 4; ++mi)
#pragma unroll
                for (int nf = 0; nf < CB; ++nf)
                    acc[mi][nf] = __builtin_amdgcn_mfma_f32_16x16x32_bf16(
                        a[mi], bfr[ks][nf], acc[mi][nf], 0, 0, 0);
        }

#pragma unroll
        for (int mi = 0; mi < 4; ++mi) {
#pragma unroll
            for (int nf = 0; nf < CB; ++nf) {
                int colg = wid * (16 * CB) + nf * 16 + lr;
#pragma unroll
                for (int rr = 0; rr < 4; ++rr) {
                    int rowg = t * 64 + mi * 16 + ((lane >> 4) << 2) + rr;
                    if (rowg < NN) {
                        float v = acc[mi][nf][rr];
                        if (colg < ZW) {
                            if (CB == 2)
                                zb[(size_t)(colg >> 4) * NN * 16 + (size_t)rowg * 16 + (colg & 15)] = f2bf(v);
                            else
                                zb[(size_t)(colg >> 3) * NN * 8 + (size_t)rowg * 8 + (colg & 7)] = f2bf(v);
                        } else {
                            int c2 = colg - ZW;
                            float vb = v + bias[c2];
                            if (YF32)
                                ((float*)yout)[(size_t)(c2 >> 3) * NN * 8 + (size_t)rowg * 8 + (c2 & 7)] = vb;
                            else
                                ((ushort*)yout)[(size_t)(c2 >> 4) * NN * 16 + (size_t)rowg * 16 + (c2 & 15)] = f2bf(vb);
                        }
                    }
                }
            }
        }
        cur ^= 1;
    }
}

// ---------------------------------------------------------------------------
// Gather 1 (XCD-affine, work-queued): h = relu(mean z1s[nbrs] + y1s), sliced.
// Slice = 16 cols (3.2MB, fits home XCD's L2). Block claims 64-node chunks
// from its home slice's cursor; falls back round-robin -> coverage guaranteed.
// Wave per node-set: 8 edge-slots x 8 lanes (uint each).
// ---------------------------------------------------------------------------
__global__ __launch_bounds__(256) void k_gather1(const ushort* __restrict__ z1s,
                                                 const ushort* __restrict__ y1s,
                                                 const int* __restrict__ rowptr,
                                                 const int* __restrict__ rowend,
                                                 const int* __restrict__ col,
                                                 int* __restrict__ cnt,
                                                 ushort* __restrict__ hbs)
{
    __shared__ int sh_c;
    const int tid  = threadIdx.x;
    const int wid  = tid >> 6, lane = tid & 63;
    const int slot = lane >> 3, off = lane & 7;
    const int s0   = xcc_id();

    for (int si = 0; si < 8; ++si) {
        int s = (s0 + si) & 7;
        const uint* zu = (const uint*)z1s + (size_t)s * NN * 8;
        const uint* yu = (const uint*)y1s + (size_t)s * NN * 8;
        uint*       hu = (uint*)hbs       + (size_t)s * NN * 8;
        while (true) {
            __syncthreads();
            if (tid == 0) sh_c = atomicAdd(&cnt[s], 1);
            __syncthreads();
            int c = sh_c;
            if (c >= NCHUNK) break;
            int nb = c * 64 + wid * 16;
            for (int j = 0; j < 16; ++j) {
                int n = nb + j;
                if (n >= NN) break;
                int beg = rowptr[n], end = rowend[n];
                float a0 = 0.f, a1 = 0.f;
                int e = beg + slot;
                for (; e + 8 < end; e += 16) {
                    int c0 = col[e], c1 = col[e + 8];
                    uint u0 = zu[(size_t)c0 * 8 + off];
                    uint u1 = zu[(size_t)c1 * 8 + off];
                    a0 += bflo(u0) + bflo(u1);
                    a1 += bfhi(u0) + bfhi(u1);
                }
                if (e < end) {
                    uint u0 = zu[(size_t)col[e] * 8 + off];
                    a0 += bflo(u0); a1 += bfhi(u0);
                }
                a0 += __shfl_xor(a0, 8);  a1 += __shfl_xor(a1, 8);
                a0 += __shfl_xor(a0, 16); a1 += __shfl_xor(a1, 16);
                a0 += __shfl_xor(a0, 32); a1 += __shfl_xor(a1, 32);
                if (slot == 0) {
                    float inv = 1.f / (float)max(end - beg, 1);
                    uint uy = yu[(size_t)n * 8 + off];
                    float h0 = fmaxf(a0 * inv + bflo(uy), 0.f);
                    float h1 = fmaxf(a1 * inv + bfhi(uy), 0.f);
                    hu[(size_t)n * 8 + off] = packbf(h0, h1);
                }
            }
        }
    }
}

// ---------------------------------------------------------------------------
// Gather 2 (XCD-affine): out = mean z2s[nbrs] + y2s, slice = 8 cols.
// 16 edge-slots x 4 lanes (uint each); out fp32 row-major (harness layout).
// ---------------------------------------------------------------------------
__global__ __launch_bounds__(256) void k_gather2(const ushort* __restrict__ z2s,
                                                 const float* __restrict__ y2s,
                                                 const int* __restrict__ rowptr,
                                                 const int* __restrict__ rowend,
                                                 const int* __restrict__ col,
                                                 int* __restrict__ cnt,
                                                 float* __restrict__ out)
{
    __shared__ int sh_c;
    const int tid  = threadIdx.x;
    const int wid  = tid >> 6, lane = tid & 63;
    const int slot = lane >> 2, off = lane & 3;
    const int s0   = xcc_id();

    for (int si = 0; si < 8; ++si) {
        int s = (s0 + si) & 7;
        const uint*   zu = (const uint*)z2s   + (size_t)s * NN * 4;
        const float2* yu = (const float2*)y2s + (size_t)s * NN * 4;
        while (true) {
            __syncthreads();
            if (tid == 0) sh_c = atomicAdd(&cnt[s], 1);
            __syncthreads();
            int c = sh_c;
            if (c >= NCHUNK) break;
            int nb = c * 64 + wid * 16;
            for (int j = 0; j < 16; ++j) {
                int n = nb + j;
                if (n >= NN) break;
                int beg = rowptr[n], end = rowend[n];
                float a0 = 0.f, a1 = 0.f;
                int e = beg + slot;
                for (; e + 16 < end; e += 32) {
                    int c0 = col[e], c1 = col[e + 16];
                    uint u0 = zu[(size_t)c0 * 4 + off];
                    uint u1 = zu[(size_t)c1 * 4 + off];
                    a0 += bflo(u0) + bflo(u1);
                    a1 += bfhi(u0) + bfhi(u1);
                }
                if (e < end) {
                    uint u0 = zu[(size_t)col[e] * 4 + off];
                    a0 += bflo(u0); a1 += bfhi(u0);
                }
                a0 += __shfl_xor(a0, 4);  a1 += __shfl_xor(a1, 4);
                a0 += __shfl_xor(a0, 8);  a1 += __shfl_xor(a1, 8);
                a0 += __shfl_xor(a0, 16); a1 += __shfl_xor(a1, 16);
                a0 += __shfl_xor(a0, 32); a1 += __shfl_xor(a1, 32);
                if (slot == 0) {
                    float inv = 1.f / (float)max(end - beg, 1);
                    float2 y = yu[(size_t)n * 4 + off];
                    float2 o;
                    o.x = a0 * inv + y.x;
                    o.y = a1 * inv + y.y;
                    ((float2*)out)[(size_t)n * 32 + s * 4 + off] = o;
                }
            }
        }
    }
}

extern "C" void kernel_launch(void* const* d_in, const int* in_sizes, int n_in,
                              void* d_out, int out_size, void* d_ws, size_t ws_size,
                              hipStream_t stream)
{
    const float* x   = (const float*)d_in[0];
    const int*   ei  = (const int*)d_in[1];
    const float* W1l = (const float*)d_in[2];
    const float* W1r = (const float*)d_in[3];
    const float* b1  = (const float*)d_in[4];
    const float* W2l = (const float*)d_in[5];
    const float* W2r = (const float*)d_in[6];
    const float* b2  = (const float*)d_in[7];
    float* out = (float*)d_out;

    const int* src = ei;
    const int* dst = ei + NE;

    // workspace layout
    int*  rowptr = (int*)d_ws;                      // NN
    int*  rowend = rowptr + NN;                     // NN
    int*  gcur   = rowend + NN;                     // 256 (NP used)
    int*  cnt1   = gcur + 200;                      // 8 (inside gcur pad)
    int*  cnt2   = gcur + 216;                      // 8
    uint* packed = (uint*)(gcur + 256);             // NP*BUCKET
    int*  colA   = (int*)(packed + (size_t)NP * BUCKET); // NP*BUCKET
    uintptr_t p = (uintptr_t)(colA + (size_t)NP * BUCKET);
    p = (p + 255) & ~(uintptr_t)255;
    ushort* WbT1 = (ushort*)p;  p += (size_t)256 * 128 * 2;
    ushort* WbT2 = (ushort*)p;  p += (size_t)128 * 128 * 2;
    p = (p + 255) & ~(uintptr_t)255;
    ushort* z1s = (ushort*)p;   p += (size_t)NN * 128 * 2;  // sliced [8][NN][16]
    ushort* y1s = (ushort*)p;   p += (size_t)NN * 128 * 2;  // sliced [8][NN][16]
    ushort* hbs = (ushort*)p;   p += (size_t)NN * 128 * 2;  // sliced [8][NN][16]
    ushort* z2s = z1s;                              // sliced [8][NN][8], alias
    float*  y2s = (float*)y1s;                      // sliced fp32 [8][NN][8], alias

    // ---- prep ----
    k_prep<<<1 + (256 * 128 + 128 * 128 + 255) / 256, 256, 0, stream>>>(
        W1l, W1r, W2l, W2r, WbT1, WbT2, gcur, cnt1, cnt2);

    // ---- CSR build ----
    k_binning<<<NBIN, 256, 0, stream>>>(src, dst, gcur, packed);
    k_pfill<<<NP, 256, 0, stream>>>(packed, gcur, rowptr, rowend, colA);

    // ---- layer 1 ----
    k_gemm<0, 2, false><<<GEMM_GB, 512, 0, stream>>>(x, WbT1, b1, z1s, y1s);
    k_gather1<<<GGRID, 256, 0, stream>>>(z1s, y1s, rowptr, rowend, colA, cnt1, hbs);

    // ---- layer 2 ----
    k_gemm<1, 1, true><<<GEMM_GB, 512, 0, stream>>>(hbs, WbT2, b2, z2s, y2s);
    k_gather2<<<GGRID, 256, 0, stream>>>(z2s, y2s, rowptr, rowend, colA, cnt2, out);
}

// Round 12
// 237.180 us; speedup vs baseline: 3.8201x; 3.8201x over previous
//
#include <hip/hip_runtime.h>

#define NN 100000
#define NE 1600000
#define PSHIFT 9
#define PSZ 512
#define NP ((NN + PSZ - 1) / PSZ)             // 196
#define BCHUNK 8192
#define NBIN ((NE + BCHUNK - 1) / BCHUNK)     // 196
#define SRCMASK 0x1FFFF                       // 17 bits (NN < 131072)
#define BUCKET 9216                           // per-partition col slots
#define GMTILES ((NN + 63) / 64)              // 1563
#define GEMM_GB 512                           // gemm grid (blocks)

typedef __attribute__((ext_vector_type(8))) short short8;
typedef __attribute__((ext_vector_type(4))) float f32x4;

__device__ __forceinline__ ushort f2bf(float f) {
    uint u = __float_as_uint(f);
    return (ushort)((u + 0x7FFFu + ((u >> 16) & 1u)) >> 16);   // RNE
}
__device__ __forceinline__ float bflo(uint u) { return __uint_as_float(u << 16); }
__device__ __forceinline__ float bfhi(uint u) { return __uint_as_float(u & 0xffff0000u); }
__device__ __forceinline__ uint packbf(float a, float b) {
    return (uint)f2bf(a) | ((uint)f2bf(b) << 16);
}

// ---------------------------------------------------------------------------
// Prep: block 0 inits gcur[p] = p*BUCKET; blocks 1.. cast weights to bf16.
// ---------------------------------------------------------------------------
__global__ __launch_bounds__(256) void k_prep(const float* __restrict__ W1l,
                                              const float* __restrict__ W1r,
                                              const float* __restrict__ W2l,
                                              const float* __restrict__ W2r,
                                              ushort* __restrict__ WbT1,
                                              ushort* __restrict__ WbT2,
                                              int* __restrict__ gcur)
{
    const int tid = threadIdx.x;
    if (blockIdx.x == 0) {
        if (tid < NP) gcur[tid] = tid * BUCKET;
        return;
    }
    int i = (blockIdx.x - 1) * 256 + tid;
    if (i < 256 * 128) {
        int c = i >> 7, k = i & 127;
        float v = (c < 128) ? W1l[k * 128 + c] : W1r[k * 128 + (c - 128)];
        WbT1[i] = f2bf(v);
    } else if (i < 256 * 128 + 128 * 128) {
        int j = i - 256 * 128;
        int c = j >> 7, k = j & 127;
        float v = (c < 64) ? W2l[k * 64 + c] : W2r[k * 64 + (c - 64)];
        WbT2[j] = f2bf(v);
    }
}

// ---------------------------------------------------------------------------
// Binning: per-block LDS histogram, one global atomic per (block,partition),
// write packed = src | (dlocal << 17) into fixed buckets.
// ---------------------------------------------------------------------------
__global__ __launch_bounds__(256) void k_binning(const int* __restrict__ src,
                                                 const int* __restrict__ dst,
                                                 int* __restrict__ gcur,
                                                 uint* __restrict__ packed)
{
    __shared__ int cnt[256];
    __shared__ int base[256];
    const int tid = threadIdx.x;
    const long e0 = (long)blockIdx.x * BCHUNK;
    cnt[tid] = 0;
    __syncthreads();
    for (int i = tid; i < BCHUNK; i += 256) {
        long e = e0 + i;
        if (e < NE) atomicAdd(&cnt[dst[e] >> PSHIFT], 1);
    }
    __syncthreads();
    if (cnt[tid] > 0) base[tid] = atomicAdd(&gcur[tid], cnt[tid]);
    cnt[tid] = 0;                       // reuse as run cursor
    __syncthreads();
    for (int i = tid; i < BCHUNK; i += 256) {
        long e = e0 + i;
        if (e < NE) {
            int d = dst[e], s = src[e];
            int p = d >> PSHIFT;
            int ofs = atomicAdd(&cnt[p], 1);
            packed[base[p] + ofs] = (uint)s | ((uint)(d & (PSZ - 1)) << 17);
        }
    }
}

// ---------------------------------------------------------------------------
// Per-partition fill: count, scan, rowptr/rowend, place col in bucket.
// ---------------------------------------------------------------------------
__global__ __launch_bounds__(256) void k_pfill(const uint* __restrict__ packed,
                                               const int* __restrict__ gcur,
                                               int* __restrict__ rowptr,
                                               int* __restrict__ rowend,
                                               int* __restrict__ col)
{
    __shared__ int cnt[PSZ];
    __shared__ int cur[PSZ];
    __shared__ int tot[256];
    const int p   = blockIdx.x;
    const int tid = threadIdx.x;
    const int beg = p * BUCKET, end = gcur[p];
    cnt[tid] = 0; cnt[tid + 256] = 0;
    __syncthreads();
    for (int i = beg + tid; i < end; i += 256)
        atomicAdd(&cnt[packed[i] >> 17], 1);
    __syncthreads();
    int v0 = cnt[tid * 2], v1 = cnt[tid * 2 + 1];
    int s  = v0 + v1;
    tot[tid] = s;
    __syncthreads();
    for (int off = 1; off < 256; off <<= 1) {
        int t = (tid >= off) ? tot[tid - off] : 0;
        __syncthreads();
        tot[tid] += t;
        __syncthreads();
    }
    int ex = tot[tid] - s + beg;
    cur[tid * 2]     = ex;
    cur[tid * 2 + 1] = ex + v0;
    int n0 = p * PSZ;
    if (n0 + tid * 2 < NN) {
        rowptr[n0 + tid * 2] = ex;
        rowend[n0 + tid * 2] = ex + v0;
    }
    if (n0 + tid * 2 + 1 < NN) {
        rowptr[n0 + tid * 2 + 1] = ex + v0;
        rowend[n0 + tid * 2 + 1] = ex + v0 + v1;
    }
    __syncthreads();
    for (int i = beg + tid; i < end; i += 256) {
        uint v = packed[i];
        int pos = atomicAdd(&cur[v >> 17], 1);
        col[pos] = (int)(v & SRCMASK);
    }
}

// ---------------------------------------------------------------------------
// Pipelined dual-GEMM: [z | y] = A @ [Wl | Wr] (+bias on y half).
// 512 threads = 8 waves; B fragments in registers; A 64x128 tile
// double-buffered in swizzled LDS (T14: write -> barrier -> issue next
// loads -> MFMA). AF32: A fp32, converted during staging. Outputs row-major.
// ---------------------------------------------------------------------------
template <bool AF32, int CB, bool YF32>
__global__ __launch_bounds__(512) void k_gemm(const void* __restrict__ Ap,
                                              const ushort* __restrict__ Bt,
                                              const float* __restrict__ bias,
                                              ushort* __restrict__ zb,
                                              void* __restrict__ yout)
{
    constexpr int ZW = CB * 64;                // z width == y width
    __shared__ ushort As[2][64 * 128];         // 2 x 16 KB

    const int tid  = threadIdx.x;
    const int wid  = tid >> 6, lane = tid & 63;
    const int lr   = lane & 15;
    const int lk   = (lane >> 4) << 3;

    short8 bfr[4][CB];
#pragma unroll
    for (int ks = 0; ks < 4; ++ks)
#pragma unroll
        for (int nf = 0; nf < CB; ++nf) {
            int colB = wid * (16 * CB) + nf * 16 + lr;
            bfr[ks][nf] = *reinterpret_cast<const short8*>(
                Bt + (size_t)colB * 128 + ks * 32 + lk);
        }

    const int p0 = tid * 16, p1 = p0 + 8192;
    const int r0 = p0 >> 8, r1 = p1 >> 8;
    const int d0 = p0 ^ ((r0 & 7) << 4);
    const int d1 = p1 ^ ((r1 & 7) << 4);
    const int e0 = (p0 & 255) >> 1;
    const int e1 = (p1 & 255) >> 1;

    const short8 zero8 = {0, 0, 0, 0, 0, 0, 0, 0};
    short8 sA0, sA1;

    auto loadA = [&](int gr, int eo) -> short8 {
        if (gr >= NN) return zero8;
        if (AF32) {
            const float* A = (const float*)Ap;
            float4 f0 = *reinterpret_cast<const float4*>(A + (size_t)gr * 128 + eo);
            float4 f1 = *reinterpret_cast<const float4*>(A + (size_t)gr * 128 + eo + 4);
            short8 v;
            v[0] = (short)f2bf(f0.x); v[1] = (short)f2bf(f0.y);
            v[2] = (short)f2bf(f0.z); v[3] = (short)f2bf(f0.w);
            v[4] = (short)f2bf(f1.x); v[5] = (short)f2bf(f1.y);
            v[6] = (short)f2bf(f1.z); v[7] = (short)f2bf(f1.w);
            return v;
        } else {
            const ushort* A = (const ushort*)Ap;
            return *reinterpret_cast<const short8*>(A + (size_t)gr * 128 + eo);
        }
    };

    int t = blockIdx.x;
    sA0 = loadA(t * 64 + r0, e0);
    sA1 = loadA(t * 64 + r1, e1);

    int cur = 0;
    for (; t < GMTILES; t += GEMM_GB) {
        char* wbase = reinterpret_cast<char*>(As[cur]);
        *reinterpret_cast<short8*>(wbase + d0) = sA0;
        *reinterpret_cast<short8*>(wbase + d1) = sA1;
        __syncthreads();

        int tn = t + GEMM_GB;
        if (tn < GMTILES) {
            sA0 = loadA(tn * 64 + r0, e0);
            sA1 = loadA(tn * 64 + r1, e1);
        }

        f32x4 acc[4][CB];
#pragma unroll
        for (int mi = 0; mi < 4; ++mi)
#pragma unroll
            for (int nf = 0; nf < CB; ++nf) acc[mi][nf] = f32x4{0.f, 0.f, 0.f, 0.f};

        const char* pA = reinterpret_cast<const char*>(As[cur]);
#pragma unroll
        for (int ks = 0; ks < 4; ++ks) {
            int k2 = (ks * 32 + lk) * 2;
            short8 a[4];
#pragma unroll
            for (int mi = 0; mi < 4; ++mi) {
                int r = mi * 16 + lr;
                int byte = (r * 256 + k2) ^ ((r & 7) << 4);
                a[mi] = *reinterpret_cast<const short8*>(pA + byte);
            }
#pragma unroll
            for (int mi = 0; mi < 4; ++mi)
#pragma unroll
                for (int nf = 0; nf < CB; ++nf)
                    acc[mi][nf] = __builtin_amdgcn_mfma_f32_16x16x32_bf16(
                        a[mi], bfr[ks][nf], acc[mi][nf], 0, 0, 0);
        }

        // epilogue: D col = lane&15, row = 4*(lane>>4) + reg
#pragma unroll
        for (int mi = 0; mi < 4; ++mi) {
#pragma unroll
            for (int nf = 0; nf < CB; ++nf) {
                int colg = wid * (16 * CB) + nf * 16 + lr;
#pragma unroll
                for (int rr = 0; rr < 4; ++rr) {
                    int rowg = t * 64 + mi * 16 + ((lane >> 4) << 2) + rr;
                    if (rowg < NN) {
                        float v = acc[mi][nf][rr];
                        if (colg < ZW) {
                            zb[(size_t)rowg * ZW + colg] = f2bf(v);
                        } else {
                            int c2 = colg - ZW;
                            if (YF32) ((float*)yout)[(size_t)rowg * ZW + c2]  = v + bias[c2];
                            else      ((ushort*)yout)[(size_t)rowg * ZW + c2] = f2bf(v + bias[c2]);
                        }
                    }
                }
            }
        }
        cur ^= 1;
    }
}

// ---------------------------------------------------------------------------
// Gather 1: hb[n] = relu( mean z1b[nbrs] + y1b[n] )  (128-wide bf16)
// Wave per node; quarters (lane>>4) take every 4th edge; uint4 loads (16B)
// -> one load round covers 4 edges; 16 edges in flight per unrolled iter.
// ---------------------------------------------------------------------------
__global__ __launch_bounds__(256) void k_gather1(const ushort* __restrict__ z1b,
                                                 const ushort* __restrict__ y1b,
                                                 const int* __restrict__ rowptr,
                                                 const int* __restrict__ rowend,
                                                 const int* __restrict__ col,
                                                 ushort* __restrict__ hb)
{
    const int w = threadIdx.x >> 6, lane = threadIdx.x & 63;
    const int n = blockIdx.x * 4 + w;
    if (n >= NN) return;
    const int quar = lane >> 4, li = lane & 15;
    const int beg = rowptr[n], end = rowend[n];
    const uint4* zu = (const uint4*)z1b;      // row = 16 uint4 (256B)
    float a0 = 0.f, a1 = 0.f, a2 = 0.f, a3 = 0.f;
    float a4 = 0.f, a5 = 0.f, a6 = 0.f, a7 = 0.f;
    int e = beg;
    for (; e + 15 < end; e += 16) {
        int s0 = col[e      + quar];
        int s1 = col[e + 4  + quar];
        int s2 = col[e + 8  + quar];
        int s3 = col[e + 12 + quar];
        uint4 u0 = zu[(size_t)s0 * 16 + li];
        uint4 u1 = zu[(size_t)s1 * 16 + li];
        uint4 u2 = zu[(size_t)s2 * 16 + li];
        uint4 u3 = zu[(size_t)s3 * 16 + li];
        a0 += bflo(u0.x) + bflo(u1.x) + bflo(u2.x) + bflo(u3.x);
        a1 += bfhi(u0.x) + bfhi(u1.x) + bfhi(u2.x) + bfhi(u3.x);
        a2 += bflo(u0.y) + bflo(u1.y) + bflo(u2.y) + bflo(u3.y);
        a3 += bfhi(u0.y) + bfhi(u1.y) + bfhi(u2.y) + bfhi(u3.y);
        a4 += bflo(u0.z) + bflo(u1.z) + bflo(u2.z) + bflo(u3.z);
        a5 += bfhi(u0.z) + bfhi(u1.z) + bfhi(u2.z) + bfhi(u3.z);
        a6 += bflo(u0.w) + bflo(u1.w) + bflo(u2.w) + bflo(u3.w);
        a7 += bfhi(u0.w) + bfhi(u1.w) + bfhi(u2.w) + bfhi(u3.w);
    }
    for (; e + 3 < end; e += 4) {
        int s0 = col[e + quar];
        uint4 u0 = zu[(size_t)s0 * 16 + li];
        a0 += bflo(u0.x); a1 += bfhi(u0.x);
        a2 += bflo(u0.y); a3 += bfhi(u0.y);
        a4 += bflo(u0.z); a5 += bfhi(u0.z);
        a6 += bflo(u0.w); a7 += bfhi(u0.w);
    }
    int rem = end - e;
    if (quar < rem) {
        int s0 = col[e + quar];
        uint4 u0 = zu[(size_t)s0 * 16 + li];
        a0 += bflo(u0.x); a1 += bfhi(u0.x);
        a2 += bflo(u0.y); a3 += bfhi(u0.y);
        a4 += bflo(u0.z); a5 += bfhi(u0.z);
        a6 += bflo(u0.w); a7 += bfhi(u0.w);
    }
    a0 += __shfl_xor(a0, 16); a1 += __shfl_xor(a1, 16);
    a2 += __shfl_xor(a2, 16); a3 += __shfl_xor(a3, 16);
    a4 += __shfl_xor(a4, 16); a5 += __shfl_xor(a5, 16);
    a6 += __shfl_xor(a6, 16); a7 += __shfl_xor(a7, 16);
    a0 += __shfl_xor(a0, 32); a1 += __shfl_xor(a1, 32);
    a2 += __shfl_xor(a2, 32); a3 += __shfl_xor(a3, 32);
    a4 += __shfl_xor(a4, 32); a5 += __shfl_xor(a5, 32);
    a6 += __shfl_xor(a6, 32); a7 += __shfl_xor(a7, 32);
    if (quar == 0) {
        float inv = 1.0f / (float)max(end - beg, 1);
        uint4 uy = ((const uint4*)y1b)[(size_t)n * 16 + li];
        uint4 o;
        o.x = packbf(fmaxf(a0 * inv + bflo(uy.x), 0.f), fmaxf(a1 * inv + bfhi(uy.x), 0.f));
        o.y = packbf(fmaxf(a2 * inv + bflo(uy.y), 0.f), fmaxf(a3 * inv + bfhi(uy.y), 0.f));
        o.z = packbf(fmaxf(a4 * inv + bflo(uy.z), 0.f), fmaxf(a5 * inv + bfhi(uy.z), 0.f));
        o.w = packbf(fmaxf(a6 * inv + bflo(uy.w), 0.f), fmaxf(a7 * inv + bfhi(uy.w), 0.f));
        ((uint4*)hb)[(size_t)n * 16 + li] = o;
    }
}

// ---------------------------------------------------------------------------
// Gather 2: out[n] = mean z2b[nbrs] + y2b[n]  (64-wide; y bf16; out fp32)
// Wave per node; quarters take every 4th edge; uint2 loads.
// ---------------------------------------------------------------------------
__global__ __launch_bounds__(256) void k_gather2(const ushort* __restrict__ z2b,
                                                 const ushort* __restrict__ y2b,
                                                 const int* __restrict__ rowptr,
                                                 const int* __restrict__ rowend,
                                                 const int* __restrict__ col,
                                                 float* __restrict__ out)
{
    const int w = threadIdx.x >> 6, lane = threadIdx.x & 63;
    const int n = blockIdx.x * 4 + w;
    if (n >= NN) return;
    const int quar = lane >> 4, li = lane & 15;
    const int beg = rowptr[n], end = rowend[n];
    const uint2* zu = (const uint2*)z2b;      // row = 16 uint2 (128B)
    float a0 = 0.f, a1 = 0.f, a2 = 0.f, a3 = 0.f;
    int e = beg;
    for (; e + 15 < end; e += 16) {
        int s0 = col[e      + quar];
        int s1 = col[e + 4  + quar];
        int s2 = col[e + 8  + quar];
        int s3 = col[e + 12 + quar];
        uint2 u0 = zu[(size_t)s0 * 16 + li];
        uint2 u1 = zu[(size_t)s1 * 16 + li];
        uint2 u2 = zu[(size_t)s2 * 16 + li];
        uint2 u3 = zu[(size_t)s3 * 16 + li];
        a0 += bflo(u0.x) + bflo(u1.x) + bflo(u2.x) + bflo(u3.x);
        a1 += bfhi(u0.x) + bfhi(u1.x) + bfhi(u2.x) + bfhi(u3.x);
        a2 += bflo(u0.y) + bflo(u1.y) + bflo(u2.y) + bflo(u3.y);
        a3 += bfhi(u0.y) + bfhi(u1.y) + bfhi(u2.y) + bfhi(u3.y);
    }
    for (; e + 3 < end; e += 4) {
        int s0 = col[e + quar];
        uint2 u0 = zu[(size_t)s0 * 16 + li];
        a0 += bflo(u0.x); a1 += bfhi(u0.x);
        a2 += bflo(u0.y); a3 += bfhi(u0.y);
    }
    int rem = end - e;
    if (quar < rem) {
        int s0 = col[e + quar];
        uint2 u0 = zu[(size_t)s0 * 16 + li];
        a0 += bflo(u0.x); a1 += bfhi(u0.x);
        a2 += bflo(u0.y); a3 += bfhi(u0.y);
    }
    a0 += __shfl_xor(a0, 16); a1 += __shfl_xor(a1, 16);
    a2 += __shfl_xor(a2, 16); a3 += __shfl_xor(a3, 16);
    a0 += __shfl_xor(a0, 32); a1 += __shfl_xor(a1, 32);
    a2 += __shfl_xor(a2, 32); a3 += __shfl_xor(a3, 32);
    if (quar == 0) {
        float inv = 1.0f / (float)max(end - beg, 1);
        uint2 uy = ((const uint2*)y2b)[(size_t)n * 16 + li];
        float4 o;
        o.x = a0 * inv + bflo(uy.x);
        o.y = a1 * inv + bfhi(uy.x);
        o.z = a2 * inv + bflo(uy.y);
        o.w = a3 * inv + bfhi(uy.y);
        ((float4*)out)[(size_t)n * 16 + li] = o;
    }
}

extern "C" void kernel_launch(void* const* d_in, const int* in_sizes, int n_in,
                              void* d_out, int out_size, void* d_ws, size_t ws_size,
                              hipStream_t stream)
{
    const float* x   = (const float*)d_in[0];
    const int*   ei  = (const int*)d_in[1];
    const float* W1l = (const float*)d_in[2];
    const float* W1r = (const float*)d_in[3];
    const float* b1  = (const float*)d_in[4];
    const float* W2l = (const float*)d_in[5];
    const float* W2r = (const float*)d_in[6];
    const float* b2  = (const float*)d_in[7];
    float* out = (float*)d_out;

    const int* src = ei;
    const int* dst = ei + NE;

    // workspace layout
    int*  rowptr = (int*)d_ws;                      // NN
    int*  rowend = rowptr + NN;                     // NN
    int*  gcur   = rowend + NN;                     // 256 (NP used)
    uint* packed = (uint*)(gcur + 256);             // NP*BUCKET
    int*  colA   = (int*)(packed + (size_t)NP * BUCKET); // NP*BUCKET
    uintptr_t p = (uintptr_t)(colA + (size_t)NP * BUCKET);
    p = (p + 255) & ~(uintptr_t)255;
    ushort* WbT1 = (ushort*)p;  p += (size_t)256 * 128 * 2;
    ushort* WbT2 = (ushort*)p;  p += (size_t)128 * 128 * 2;
    p = (p + 255) & ~(uintptr_t)255;
    ushort* z1b = (ushort*)p;   p += (size_t)NN * 128 * 2;  // row-major bf16
    ushort* y1b = (ushort*)p;   p += (size_t)NN * 128 * 2;  // row-major bf16
    ushort* hb  = (ushort*)p;   p += (size_t)NN * 128 * 2;  // row-major bf16
    ushort* z2b = z1b;                              // [NN][64] bf16, alias
    ushort* y2b = y1b;                              // [NN][64] bf16, alias

    // ---- prep (gcur init + weight cast) ----
    k_prep<<<1 + (256 * 128 + 128 * 128 + 255) / 256, 256, 0, stream>>>(
        W1l, W1r, W2l, W2r, WbT1, WbT2, gcur);

    // ---- CSR build (fixed buckets) ----
    k_binning<<<NBIN, 256, 0, stream>>>(src, dst, gcur, packed);
    k_pfill<<<NP, 256, 0, stream>>>(packed, gcur, rowptr, rowend, colA);

    // ---- layer 1 ----
    k_gemm<true, 2, false><<<GEMM_GB, 512, 0, stream>>>(x, WbT1, b1, z1b, y1b);
    k_gather1<<<(NN + 3) / 4, 256, 0, stream>>>(z1b, y1b, rowptr, rowend, colA, hb);

    // ---- layer 2 ----
    k_gemm<false, 1, false><<<GEMM_GB, 512, 0, stream>>>(hb, WbT2, b2, z2b, y2b);
    k_gather2<<<(NN + 3) / 4, 256, 0, stream>>>(z2b, y2b, rowptr, rowend, colA, out);
}

// Round 13
// 228.805 us; speedup vs baseline: 3.9599x; 1.0366x over previous
//
#include <hip/hip_runtime.h>

#define NN 100000
#define NE 1600000
#define PSHIFT 9
#define PSZ 512
#define NP ((NN + PSZ - 1) / PSZ)             // 196
#define BCHUNK 4096
#define NBIN ((NE + BCHUNK - 1) / BCHUNK)     // 391
#define SRCMASK 0x1FFFF                       // 17 bits (NN < 131072)
#define BUCKET 9216                           // per-partition col slots
#define GMTILES ((NN + 63) / 64)              // 1563
#define GEMM_GB 512                           // gemm grid (blocks)

typedef __attribute__((ext_vector_type(8))) short short8;
typedef __attribute__((ext_vector_type(4))) float f32x4;
typedef __attribute__((ext_vector_type(2))) float f32x2;

__device__ __forceinline__ ushort f2bf(float f) {
    uint u = __float_as_uint(f);
    return (ushort)((u + 0x7FFFu + ((u >> 16) & 1u)) >> 16);   // RNE
}
__device__ __forceinline__ float bflo(uint u) { return __uint_as_float(u << 16); }
__device__ __forceinline__ float bfhi(uint u) { return __uint_as_float(u & 0xffff0000u); }
__device__ __forceinline__ uint packbf(float a, float b) {
    return (uint)f2bf(a) | ((uint)f2bf(b) << 16);
}
// Packed accumulate of one uint (2 bf16). Main-loop fast path: hi half keeps
// the neighbor's 16 junk mantissa bits (adds <=2^-8 relative noise, ~+0.01
// absmax worst-case here) -> 2 VALU ops + 1 v_pk_add_f32 instead of 4 ops.
__device__ __forceinline__ void acc2(f32x2& A, uint u) {
    f32x2 v;
    v.x = __uint_as_float(u << 16);
    v.y = __uint_as_float(u);          // junk-mantissa hi (see note)
    A += v;                            // v_pk_add_f32
}
__device__ __forceinline__ void acc2x(f32x2& A, uint u) {   // exact (tails)
    f32x2 v;
    v.x = bflo(u);
    v.y = bfhi(u);
    A += v;
}

// ---------------------------------------------------------------------------
// Prep: block 0 inits gcur[p] = p*BUCKET; blocks 1.. cast weights to bf16.
// ---------------------------------------------------------------------------
__global__ __launch_bounds__(256) void k_prep(const float* __restrict__ W1l,
                                              const float* __restrict__ W1r,
                                              const float* __restrict__ W2l,
                                              const float* __restrict__ W2r,
                                              ushort* __restrict__ WbT1,
                                              ushort* __restrict__ WbT2,
                                              int* __restrict__ gcur)
{
    const int tid = threadIdx.x;
    if (blockIdx.x == 0) {
        if (tid < NP) gcur[tid] = tid * BUCKET;
        return;
    }
    int i = (blockIdx.x - 1) * 256 + tid;
    if (i < 256 * 128) {
        int c = i >> 7, k = i & 127;
        float v = (c < 128) ? W1l[k * 128 + c] : W1r[k * 128 + (c - 128)];
        WbT1[i] = f2bf(v);
    } else if (i < 256 * 128 + 128 * 128) {
        int j = i - 256 * 128;
        int c = j >> 7, k = j & 127;
        float v = (c < 64) ? W2l[k * 64 + c] : W2r[k * 64 + (c - 64)];
        WbT2[j] = f2bf(v);
    }
}

// ---------------------------------------------------------------------------
// Binning: per-block LDS histogram, one global atomic per (block,partition),
// write packed = src | (dlocal << 17) into fixed buckets.
// ---------------------------------------------------------------------------
__global__ __launch_bounds__(256) void k_binning(const int* __restrict__ src,
                                                 const int* __restrict__ dst,
                                                 int* __restrict__ gcur,
                                                 uint* __restrict__ packed)
{
    __shared__ int cnt[256];
    __shared__ int base[256];
    const int tid = threadIdx.x;
    const long e0 = (long)blockIdx.x * BCHUNK;
    cnt[tid] = 0;
    __syncthreads();
    for (int i = tid; i < BCHUNK; i += 256) {
        long e = e0 + i;
        if (e < NE) atomicAdd(&cnt[dst[e] >> PSHIFT], 1);
    }
    __syncthreads();
    if (cnt[tid] > 0) base[tid] = atomicAdd(&gcur[tid], cnt[tid]);
    cnt[tid] = 0;                       // reuse as run cursor
    __syncthreads();
    for (int i = tid; i < BCHUNK; i += 256) {
        long e = e0 + i;
        if (e < NE) {
            int d = dst[e], s = src[e];
            int p = d >> PSHIFT;
            int ofs = atomicAdd(&cnt[p], 1);
            packed[base[p] + ofs] = (uint)s | ((uint)(d & (PSZ - 1)) << 17);
        }
    }
}

// ---------------------------------------------------------------------------
// Per-partition fill: count, scan, rowptr/rowend, place col in bucket.
// ---------------------------------------------------------------------------
__global__ __launch_bounds__(256) void k_pfill(const uint* __restrict__ packed,
                                               const int* __restrict__ gcur,
                                               int* __restrict__ rowptr,
                                               int* __restrict__ rowend,
                                               int* __restrict__ col)
{
    __shared__ int cnt[PSZ];
    __shared__ int cur[PSZ];
    __shared__ int tot[256];
    const int p   = blockIdx.x;
    const int tid = threadIdx.x;
    const int beg = p * BUCKET, end = gcur[p];
    cnt[tid] = 0; cnt[tid + 256] = 0;
    __syncthreads();
    for (int i = beg + tid; i < end; i += 256)
        atomicAdd(&cnt[packed[i] >> 17], 1);
    __syncthreads();
    int v0 = cnt[tid * 2], v1 = cnt[tid * 2 + 1];
    int s  = v0 + v1;
    tot[tid] = s;
    __syncthreads();
    for (int off = 1; off < 256; off <<= 1) {
        int t = (tid >= off) ? tot[tid - off] : 0;
        __syncthreads();
        tot[tid] += t;
        __syncthreads();
    }
    int ex = tot[tid] - s + beg;
    cur[tid * 2]     = ex;
    cur[tid * 2 + 1] = ex + v0;
    int n0 = p * PSZ;
    if (n0 + tid * 2 < NN) {
        rowptr[n0 + tid * 2] = ex;
        rowend[n0 + tid * 2] = ex + v0;
    }
    if (n0 + tid * 2 + 1 < NN) {
        rowptr[n0 + tid * 2 + 1] = ex + v0;
        rowend[n0 + tid * 2 + 1] = ex + v0 + v1;
    }
    __syncthreads();
    for (int i = beg + tid; i < end; i += 256) {
        uint v = packed[i];
        int pos = atomicAdd(&cur[v >> 17], 1);
        col[pos] = (int)(v & SRCMASK);
    }
}

// ---------------------------------------------------------------------------
// Pipelined dual-GEMM: [z | y] = A @ [Wl | Wr] (+bias on y half).
// 512 threads = 8 waves; B fragments in registers; A 64x128 tile
// double-buffered in swizzled LDS (T14). AF32: A fp32, converted in staging.
// ---------------------------------------------------------------------------
template <bool AF32, int CB, bool YF32>
__global__ __launch_bounds__(512) void k_gemm(const void* __restrict__ Ap,
                                              const ushort* __restrict__ Bt,
                                              const float* __restrict__ bias,
                                              ushort* __restrict__ zb,
                                              void* __restrict__ yout)
{
    constexpr int ZW = CB * 64;                // z width == y width
    __shared__ ushort As[2][64 * 128];         // 2 x 16 KB

    const int tid  = threadIdx.x;
    const int wid  = tid >> 6, lane = tid & 63;
    const int lr   = lane & 15;
    const int lk   = (lane >> 4) << 3;

    short8 bfr[4][CB];
#pragma unroll
    for (int ks = 0; ks < 4; ++ks)
#pragma unroll
        for (int nf = 0; nf < CB; ++nf) {
            int colB = wid * (16 * CB) + nf * 16 + lr;
            bfr[ks][nf] = *reinterpret_cast<const short8*>(
                Bt + (size_t)colB * 128 + ks * 32 + lk);
        }

    const int p0 = tid * 16, p1 = p0 + 8192;
    const int r0 = p0 >> 8, r1 = p1 >> 8;
    const int d0 = p0 ^ ((r0 & 7) << 4);
    const int d1 = p1 ^ ((r1 & 7) << 4);
    const int e0 = (p0 & 255) >> 1;
    const int e1 = (p1 & 255) >> 1;

    const short8 zero8 = {0, 0, 0, 0, 0, 0, 0, 0};
    short8 sA0, sA1;

    auto loadA = [&](int gr, int eo) -> short8 {
        if (gr >= NN) return zero8;
        if (AF32) {
            const float* A = (const float*)Ap;
            float4 f0 = *reinterpret_cast<const float4*>(A + (size_t)gr * 128 + eo);
            float4 f1 = *reinterpret_cast<const float4*>(A + (size_t)gr * 128 + eo + 4);
            short8 v;
            v[0] = (short)f2bf(f0.x); v[1] = (short)f2bf(f0.y);
            v[2] = (short)f2bf(f0.z); v[3] = (short)f2bf(f0.w);
            v[4] = (short)f2bf(f1.x); v[5] = (short)f2bf(f1.y);
            v[6] = (short)f2bf(f1.z); v[7] = (short)f2bf(f1.w);
            return v;
        } else {
            const ushort* A = (const ushort*)Ap;
            return *reinterpret_cast<const short8*>(A + (size_t)gr * 128 + eo);
        }
    };

    int t = blockIdx.x;
    sA0 = loadA(t * 64 + r0, e0);
    sA1 = loadA(t * 64 + r1, e1);

    int cur = 0;
    for (; t < GMTILES; t += GEMM_GB) {
        char* wbase = reinterpret_cast<char*>(As[cur]);
        *reinterpret_cast<short8*>(wbase + d0) = sA0;
        *reinterpret_cast<short8*>(wbase + d1) = sA1;
        __syncthreads();

        int tn = t + GEMM_GB;
        if (tn < GMTILES) {
            sA0 = loadA(tn * 64 + r0, e0);
            sA1 = loadA(tn * 64 + r1, e1);
        }

        f32x4 acc[4][CB];
#pragma unroll
        for (int mi = 0; mi < 4; ++mi)
#pragma unroll
            for (int nf = 0; nf < CB; ++nf) acc[mi][nf] = f32x4{0.f, 0.f, 0.f, 0.f};

        const char* pA = reinterpret_cast<const char*>(As[cur]);
#pragma unroll
        for (int ks = 0; ks < 4; ++ks) {
            int k2 = (ks * 32 + lk) * 2;
            short8 a[4];
#pragma unroll
            for (int mi = 0; mi < 4; ++mi) {
                int r = mi * 16 + lr;
                int byte = (r * 256 + k2) ^ ((r & 7) << 4);
                a[mi] = *reinterpret_cast<const short8*>(pA + byte);
            }
#pragma unroll
            for (int mi = 0; mi < 4; ++mi)
#pragma unroll
                for (int nf = 0; nf < CB; ++nf)
                    acc[mi][nf] = __builtin_amdgcn_mfma_f32_16x16x32_bf16(
                        a[mi], bfr[ks][nf], acc[mi][nf], 0, 0, 0);
        }

        // epilogue: D col = lane&15, row = 4*(lane>>4) + reg
#pragma unroll
        for (int mi = 0; mi < 4; ++mi) {
#pragma unroll
            for (int nf = 0; nf < CB; ++nf) {
                int colg = wid * (16 * CB) + nf * 16 + lr;
#pragma unroll
                for (int rr = 0; rr < 4; ++rr) {
                    int rowg = t * 64 + mi * 16 + ((lane >> 4) << 2) + rr;
                    if (rowg < NN) {
                        float v = acc[mi][nf][rr];
                        if (colg < ZW) {
                            zb[(size_t)rowg * ZW + colg] = f2bf(v);
                        } else {
                            int c2 = colg - ZW;
                            if (YF32) ((float*)yout)[(size_t)rowg * ZW + c2]  = v + bias[c2];
                            else      ((ushort*)yout)[(size_t)rowg * ZW + c2] = f2bf(v + bias[c2]);
                        }
                    }
                }
            }
        }
        cur ^= 1;
    }
}

// ---------------------------------------------------------------------------
// Gather 1: hb[n] = relu( mean z1b[nbrs] + y1b[n] )  (128-wide bf16)
// Wave per node; quarters take every 4th edge; uint4 loads; col prefetched
// one iteration ahead (breaks col->z round-trip chain); packed f32x2 acc.
// ---------------------------------------------------------------------------
__global__ __launch_bounds__(256) void k_gather1(const ushort* __restrict__ z1b,
                                                 const ushort* __restrict__ y1b,
                                                 const int* __restrict__ rowptr,
                                                 const int* __restrict__ rowend,
                                                 const int* __restrict__ col,
                                                 ushort* __restrict__ hb)
{
    const int w = threadIdx.x >> 6, lane = threadIdx.x & 63;
    const int n = blockIdx.x * 4 + w;
    if (n >= NN) return;
    const int quar = lane >> 4, li = lane & 15;
    const int beg = rowptr[n], end = rowend[n];
    const uint4* zu = (const uint4*)z1b;      // row = 16 uint4 (256B)
    uint4 uy = ((const uint4*)y1b)[(size_t)n * 16 + li];   // hoisted

    f32x2 A0 = {0.f, 0.f}, A1 = {0.f, 0.f}, A2 = {0.f, 0.f}, A3 = {0.f, 0.f};
    int e = beg;
    int c0 = 0, c1 = 0, c2 = 0, c3 = 0;
    bool have = (e + 15 < end);
    if (have) {
        c0 = col[e + quar];      c1 = col[e + 4 + quar];
        c2 = col[e + 8 + quar];  c3 = col[e + 12 + quar];
    }
    while (have) {
        uint4 u0 = zu[(size_t)c0 * 16 + li];
        uint4 u1 = zu[(size_t)c1 * 16 + li];
        uint4 u2 = zu[(size_t)c2 * 16 + li];
        uint4 u3 = zu[(size_t)c3 * 16 + li];
        e += 16;
        have = (e + 15 < end);
        if (have) {                        // prefetch next quad of indices
            c0 = col[e + quar];      c1 = col[e + 4 + quar];
            c2 = col[e + 8 + quar];  c3 = col[e + 12 + quar];
        }
        acc2(A0, u0.x); acc2(A1, u0.y); acc2(A2, u0.z); acc2(A3, u0.w);
        acc2(A0, u1.x); acc2(A1, u1.y); acc2(A2, u1.z); acc2(A3, u1.w);
        acc2(A0, u2.x); acc2(A1, u2.y); acc2(A2, u2.z); acc2(A3, u2.w);
        acc2(A0, u3.x); acc2(A1, u3.y); acc2(A2, u3.z); acc2(A3, u3.w);
    }
    for (; e + 3 < end; e += 4) {
        uint4 u0 = zu[(size_t)col[e + quar] * 16 + li];
        acc2x(A0, u0.x); acc2x(A1, u0.y); acc2x(A2, u0.z); acc2x(A3, u0.w);
    }
    int rem = end - e;
    if (quar < rem) {
        uint4 u0 = zu[(size_t)col[e + quar] * 16 + li];
        acc2x(A0, u0.x); acc2x(A1, u0.y); acc2x(A2, u0.z); acc2x(A3, u0.w);
    }
    A0.x += __shfl_xor(A0.x, 16); A0.y += __shfl_xor(A0.y, 16);
    A1.x += __shfl_xor(A1.x, 16); A1.y += __shfl_xor(A1.y, 16);
    A2.x += __shfl_xor(A2.x, 16); A2.y += __shfl_xor(A2.y, 16);
    A3.x += __shfl_xor(A3.x, 16); A3.y += __shfl_xor(A3.y, 16);
    A0.x += __shfl_xor(A0.x, 32); A0.y += __shfl_xor(A0.y, 32);
    A1.x += __shfl_xor(A1.x, 32); A1.y += __shfl_xor(A1.y, 32);
    A2.x += __shfl_xor(A2.x, 32); A2.y += __shfl_xor(A2.y, 32);
    A3.x += __shfl_xor(A3.x, 32); A3.y += __shfl_xor(A3.y, 32);
    if (quar == 0) {
        float inv = 1.0f / (float)max(end - beg, 1);
        uint4 o;
        o.x = packbf(fmaxf(A0.x * inv + bflo(uy.x), 0.f), fmaxf(A0.y * inv + bfhi(uy.x), 0.f));
        o.y = packbf(fmaxf(A1.x * inv + bflo(uy.y), 0.f), fmaxf(A1.y * inv + bfhi(uy.y), 0.f));
        o.z = packbf(fmaxf(A2.x * inv + bflo(uy.z), 0.f), fmaxf(A2.y * inv + bfhi(uy.z), 0.f));
        o.w = packbf(fmaxf(A3.x * inv + bflo(uy.w), 0.f), fmaxf(A3.y * inv + bfhi(uy.w), 0.f));
        ((uint4*)hb)[(size_t)n * 16 + li] = o;
    }
}

// ---------------------------------------------------------------------------
// Gather 2: out[n] = mean z2b[nbrs] + y2b[n]  (64-wide; y bf16; out fp32)
// Wave per node; quarters take every 4th edge; uint2 loads; col prefetch;
// packed f32x2 accumulation.
// ---------------------------------------------------------------------------
__global__ __launch_bounds__(256) void k_gather2(const ushort* __restrict__ z2b,
                                                 const ushort* __restrict__ y2b,
                                                 const int* __restrict__ rowptr,
                                                 const int* __restrict__ rowend,
                                                 const int* __restrict__ col,
                                                 float* __restrict__ out)
{
    const int w = threadIdx.x >> 6, lane = threadIdx.x & 63;
    const int n = blockIdx.x * 4 + w;
    if (n >= NN) return;
    const int quar = lane >> 4, li = lane & 15;
    const int beg = rowptr[n], end = rowend[n];
    const uint2* zu = (const uint2*)z2b;      // row = 16 uint2 (128B)
    uint2 uy = ((const uint2*)y2b)[(size_t)n * 16 + li];   // hoisted

    f32x2 A0 = {0.f, 0.f}, A1 = {0.f, 0.f};
    int e = beg;
    int c0 = 0, c1 = 0, c2 = 0, c3 = 0;
    bool have = (e + 15 < end);
    if (have) {
        c0 = col[e + quar];      c1 = col[e + 4 + quar];
        c2 = col[e + 8 + quar];  c3 = col[e + 12 + quar];
    }
    while (have) {
        uint2 u0 = zu[(size_t)c0 * 16 + li];
        uint2 u1 = zu[(size_t)c1 * 16 + li];
        uint2 u2 = zu[(size_t)c2 * 16 + li];
        uint2 u3 = zu[(size_t)c3 * 16 + li];
        e += 16;
        have = (e + 15 < end);
        if (have) {
            c0 = col[e + quar];      c1 = col[e + 4 + quar];
            c2 = col[e + 8 + quar];  c3 = col[e + 12 + quar];
        }
        acc2(A0, u0.x); acc2(A1, u0.y);
        acc2(A0, u1.x); acc2(A1, u1.y);
        acc2(A0, u2.x); acc2(A1, u2.y);
        acc2(A0, u3.x); acc2(A1, u3.y);
    }
    for (; e + 3 < end; e += 4) {
        uint2 u0 = zu[(size_t)col[e + quar] * 16 + li];
        acc2x(A0, u0.x); acc2x(A1, u0.y);
    }
    int rem = end - e;
    if (quar < rem) {
        uint2 u0 = zu[(size_t)col[e + quar] * 16 + li];
        acc2x(A0, u0.x); acc2x(A1, u0.y);
    }
    A0.x += __shfl_xor(A0.x, 16); A0.y += __shfl_xor(A0.y, 16);
    A1.x += __shfl_xor(A1.x, 16); A1.y += __shfl_xor(A1.y, 16);
    A0.x += __shfl_xor(A0.x, 32); A0.y += __shfl_xor(A0.y, 32);
    A1.x += __shfl_xor(A1.x, 32); A1.y += __shfl_xor(A1.y, 32);
    if (quar == 0) {
        float inv = 1.0f / (float)max(end - beg, 1);
        float4 o;
        o.x = A0.x * inv + bflo(uy.x);
        o.y = A0.y * inv + bfhi(uy.x);
        o.z = A1.x * inv + bflo(uy.y);
        o.w = A1.y * inv + bfhi(uy.y);
        ((float4*)out)[(size_t)n * 16 + li] = o;
    }
}

extern "C" void kernel_launch(void* const* d_in, const int* in_sizes, int n_in,
                              void* d_out, int out_size, void* d_ws, size_t ws_size,
                              hipStream_t stream)
{
    const float* x   = (const float*)d_in[0];
    const int*   ei  = (const int*)d_in[1];
    const float* W1l = (const float*)d_in[2];
    const float* W1r = (const float*)d_in[3];
    const float* b1  = (const float*)d_in[4];
    const float* W2l = (const float*)d_in[5];
    const float* W2r = (const float*)d_in[6];
    const float* b2  = (const float*)d_in[7];
    float* out = (float*)d_out;

    const int* src = ei;
    const int* dst = ei + NE;

    // workspace layout
    int*  rowptr = (int*)d_ws;                      // NN
    int*  rowend = rowptr + NN;                     // NN
    int*  gcur   = rowend + NN;                     // 256 (NP used)
    uint* packed = (uint*)(gcur + 256);             // NP*BUCKET
    int*  colA   = (int*)(packed + (size_t)NP * BUCKET); // NP*BUCKET
    uintptr_t p = (uintptr_t)(colA + (size_t)NP * BUCKET);
    p = (p + 255) & ~(uintptr_t)255;
    ushort* WbT1 = (ushort*)p;  p += (size_t)256 * 128 * 2;
    ushort* WbT2 = (ushort*)p;  p += (size_t)128 * 128 * 2;
    p = (p + 255) & ~(uintptr_t)255;
    ushort* z1b = (ushort*)p;   p += (size_t)NN * 128 * 2;  // row-major bf16
    ushort* y1b = (ushort*)p;   p += (size_t)NN * 128 * 2;  // row-major bf16
    ushort* hb  = (ushort*)p;   p += (size_t)NN * 128 * 2;  // row-major bf16
    ushort* z2b = z1b;                              // [NN][64] bf16, alias
    ushort* y2b = y1b;                              // [NN][64] bf16, alias

    // ---- prep (gcur init + weight cast) ----
    k_prep<<<1 + (256 * 128 + 128 * 128 + 255) / 256, 256, 0, stream>>>(
        W1l, W1r, W2l, W2r, WbT1, WbT2, gcur);

    // ---- CSR build (fixed buckets) ----
    k_binning<<<NBIN, 256, 0, stream>>>(src, dst, gcur, packed);
    k_pfill<<<NP, 256, 0, stream>>>(packed, gcur, rowptr, rowend, colA);

    // ---- layer 1 ----
    k_gemm<true, 2, false><<<GEMM_GB, 512, 0, stream>>>(x, WbT1, b1, z1b, y1b);
    k_gather1<<<(NN + 3) / 4, 256, 0, stream>>>(z1b, y1b, rowptr, rowend, colA, hb);

    // ---- layer 2 ----
    k_gemm<false, 1, false><<<GEMM_GB, 512, 0, stream>>>(hb, WbT2, b2, z2b, y2b);
    k_gather2<<<(NN + 3) / 4, 256, 0, stream>>>(z2b, y2b, rowptr, rowend, colA, out);
}